// Round 1
// baseline (3254.581 us; speedup 1.0000x reference)
//
#include <hip/hip_runtime.h>
#include <hip/hip_bf16.h>

#define NHEADS 6
#define CIN 192
#define HD 32
#define IMG 256
#define NPIX 64

// Fully fused: depthwise 3x3 + pointwise 1x1 (->qkv) + windowed cosine attention.
// One block per 8x8 window. 256 threads = 4 waves.
__global__ __launch_bounds__(256, 2)
void fused_winattn(const float* __restrict__ x,
                   const float* __restrict__ dww,
                   const float* __restrict__ dwb,
                   const float* __restrict__ pww,
                   const float* __restrict__ pwb,
                   float* __restrict__ out) {
    // y (depthwise out) as bf16, padded to 194 (stride 97 dwords -> conflict-free)
    __shared__ unsigned short ys[NPIX][194];
    __shared__ float qh[NPIX][33];
    __shared__ float kh[NPIX][33];
    __shared__ float vh[NPIX][33];
    __shared__ float attn[NPIX][65];
    __shared__ float qin[NPIX];
    __shared__ float kin[NPIX];

    const int wb = blockIdx.x;
    const int b  = wb >> 10;
    const int wy = (wb >> 5) & 31;
    const int wx = wb & 31;
    const int r0 = wy << 3, c0 = wx << 3;
    const int tid  = threadIdx.x;
    const int lane = tid & 63;
    const int wave = __builtin_amdgcn_readfirstlane(tid >> 6);
    const int pi = lane >> 3, pj = lane & 7;
    const int py = r0 + pi, px = c0 + pj;

    // ---------- depthwise 3x3 + bias -> ys (bf16) ----------
    // lane = pixel, wave strides over channels (c uniform per wave -> scalar weight loads)
    for (int c = wave; c < CIN; c += 4) {
        const float* xp = x + (((size_t)(b * CIN + c)) << 16);
        float acc = dwb[c];
#pragma unroll
        for (int di = 0; di < 3; ++di) {
            const int yy = py + di - 1;
            const bool yok = (unsigned)yy < (unsigned)IMG;
#pragma unroll
            for (int dj = 0; dj < 3; ++dj) {
                const int xx = px + dj - 1;
                const float xv = (yok && (unsigned)xx < (unsigned)IMG) ? xp[yy * IMG + xx] : 0.0f;
                acc += xv * dww[c * 9 + di * 3 + dj];
            }
        }
        __hip_bfloat16 t = __float2bfloat16(acc);
        ys[lane][c] = *reinterpret_cast<unsigned short*>(&t);
    }
    __syncthreads();

    // ---------- per-head: pointwise -> q,k,v ; cosine attention ; output ----------
    for (int h = 0; h < NHEADS; ++h) {
        // pointwise: 96 output channels for this head (32 q, 32 k, 32 v);
        // each wave owns 24 of them, in blocks of 8 (blocks never cross q/k/v boundary).
        for (int lb = wave * 24; lb < wave * 24 + 24; lb += 8) {
            const int g  = lb >> 5;       // 0=q 1=k 2=v
            const int d0 = lb & 31;
            const int ocbase = g * CIN + h * HD + d0;
            const float* wrow = pww + (size_t)ocbase * CIN;
            float acc[8];
#pragma unroll
            for (int k = 0; k < 8; ++k) acc[k] = pwb[ocbase + k];
            for (int c = 0; c < CIN; c += 2) {
                const unsigned pair = *(const unsigned*)&ys[lane][c];
                const float y0 = __uint_as_float(pair << 16);
                const float y1 = __uint_as_float(pair & 0xffff0000u);
#pragma unroll
                for (int k = 0; k < 8; ++k) {
                    acc[k] += y0 * wrow[k * CIN + c];
                    acc[k] += y1 * wrow[k * CIN + c + 1];
                }
            }
            float (*dst)[33] = (g == 0) ? qh : (g == 1) ? kh : vh;
#pragma unroll
            for (int k = 0; k < 8; ++k) dst[lane][d0 + k] = acc[k];
        }
        __syncthreads();

        // inverse L2 norms of q and k rows
        if (tid < 128) {
            const int row = tid & 63;
            const float (*src)[33] = (tid < 64) ? qh : kh;
            float s = 0.f;
#pragma unroll
            for (int d = 0; d < HD; ++d) { const float v = src[row][d]; s += v * v; }
            const float inv = 1.0f / fmaxf(sqrtf(s), 1e-12f);
            if (tid < 64) qin[row] = inv; else kin[row] = inv;
        }
        __syncthreads();

        // QK^T + softmax: each wave does 16 query rows; lane = key index
        for (int i = 0; i < 16; ++i) {
            const int p = wave * 16 + i;
            float dot = 0.f;
#pragma unroll
            for (int d = 0; d < HD; ++d) dot += qh[p][d] * kh[lane][d];
            const float logit = dot * qin[p] * kin[lane];
            float mx = logit;
#pragma unroll
            for (int off = 32; off; off >>= 1) mx = fmaxf(mx, __shfl_xor(mx, off));
            const float e = __expf(logit - mx);
            float s = e;
#pragma unroll
            for (int off = 32; off; off >>= 1) s += __shfl_xor(s, off);
            attn[p][lane] = e / s;
        }
        __syncthreads();

        // PV: lane = query pixel; wave owns 8 of the 32 dims -> contiguous-in-W stores
        float oacc[8];
#pragma unroll
        for (int k = 0; k < 8; ++k) oacc[k] = 0.f;
        for (int m = 0; m < NPIX; ++m) {
            const float a = attn[lane][m];
#pragma unroll
            for (int k = 0; k < 8; ++k) oacc[k] += a * vh[m][wave * 8 + k];
        }
        {
            const size_t obase = (((size_t)(b * CIN + h * HD + wave * 8)) << 16)
                               + (size_t)py * IMG + px;
#pragma unroll
            for (int k = 0; k < 8; ++k)
                out[obase + ((size_t)k << 16)] = oacc[k];
        }
        __syncthreads();
    }
}

extern "C" void kernel_launch(void* const* d_in, const int* in_sizes, int n_in,
                              void* d_out, int out_size, void* d_ws, size_t ws_size,
                              hipStream_t stream) {
    const float* x   = (const float*)d_in[0];
    const float* dww = (const float*)d_in[1];
    const float* dwb = (const float*)d_in[2];
    const float* pww = (const float*)d_in[3];
    const float* pwb = (const float*)d_in[4];
    float* out = (float*)d_out;
    dim3 grid(4 * 32 * 32);
    dim3 block(256);
    hipLaunchKernelGGL(fused_winattn, grid, block, 0, stream, x, dww, dwb, pww, pwb, out);
}

// Round 2
// 482.496 us; speedup vs baseline: 6.7453x; 6.7453x over previous
//
#include <hip/hip_runtime.h>
#include <hip/hip_bf16.h>

typedef float f32x4 __attribute__((ext_vector_type(4)));
typedef short bf16x8 __attribute__((ext_vector_type(8)));
typedef unsigned short u16;

#define NHEADS 6
#define CIN 192
#define HD 32
#define IMG 256
#define YS_ST 200   // bf16 elems; 400B row stride (16B aligned)
#define QK_ST 40    // 80B
#define VT_ST 72    // 144B
#define P_ST  72    // 144B

__device__ __forceinline__ u16 f2bf(float f) {
    __hip_bfloat16 t = __float2bfloat16(f);
    return *reinterpret_cast<u16*>(&t);
}

// One block per 8x8 window; 256 threads = 4 waves.
// depthwise 3x3 (fp32) -> ys bf16 in LDS -> per-head: pointwise GEMM (MFMA),
// cosine QK^T (MFMA) + register softmax, PV (MFMA) -> coalesced f32x4 stores.
__global__ __launch_bounds__(256, 3)
void fused_winattn_mfma(const float* __restrict__ x,
                        const float* __restrict__ dww,
                        const float* __restrict__ dwb,
                        const float* __restrict__ pww,
                        const float* __restrict__ pwb,
                        const u16* __restrict__ wbf,   // bf16 weights in ws, or null
                        float* __restrict__ out) {
    __shared__ u16 ys[64][YS_ST];
    __shared__ u16 qs[64][QK_ST];
    __shared__ u16 kk_s[64][QK_ST];
    __shared__ u16 vt[HD][VT_ST];     // V^T: [dim][kv]
    __shared__ u16 ps[64][P_ST];      // P: [q][kv]
    __shared__ float qin[64], kin[64];

    const int wb = blockIdx.x;
    const int b  = wb >> 10;
    const int wy = (wb >> 5) & 31;
    const int wx = wb & 31;
    const int r0 = wy << 3, c0 = wx << 3;
    const int tid  = threadIdx.x;
    const int lane = tid & 63;
    const int wave = __builtin_amdgcn_readfirstlane(tid >> 6);
    const int l15 = lane & 15;
    const int l4  = lane >> 4;

    // ---------- depthwise 3x3 + bias -> ys bf16 ----------
    {
        const int pi = lane >> 3, pj = lane & 7;
        const int py = r0 + pi, px = c0 + pj;
        for (int c = wave; c < CIN; c += 4) {
            const float* xp = x + (((size_t)(b * CIN + c)) << 16);
            float acc = dwb[c];
#pragma unroll
            for (int di = 0; di < 3; ++di) {
                const int yy = py + di - 1;
                const bool yok = (unsigned)yy < (unsigned)IMG;
#pragma unroll
                for (int dj = 0; dj < 3; ++dj) {
                    const int xx = px + dj - 1;
                    const float xv = (yok && (unsigned)xx < (unsigned)IMG) ? xp[yy * IMG + xx] : 0.f;
                    acc += xv * dww[c * 9 + di * 3 + dj];
                }
            }
            ys[lane][c] = f2bf(acc);
        }
    }
    __syncthreads();

    // ---------- A-fragments of ys (reused for all heads) ----------
    // wave = (wr: 32-px row group, wc: 48-oc col group)
    const int wr = wave >> 1, wc = wave & 1;
    bf16x8 afr[2][6];
#pragma unroll
    for (int rt = 0; rt < 2; ++rt) {
        const u16* ab = &ys[wr * 32 + rt * 16 + l15][l4 * 8];
#pragma unroll
        for (int kt = 0; kt < 6; ++kt)
            afr[rt][kt] = *(const bf16x8*)(ab + kt * 32);
    }

    for (int h = 0; h < NHEADS; ++h) {
        // ---------- pointwise: 64x48x192 GEMM per wave-colgroup ----------
#pragma unroll
        for (int ctl = 0; ctl < 3; ++ctl) {
            const int t  = wc * 3 + ctl;      // abs col tile 0..5
            const int g  = t >> 1;            // 0=q 1=k 2=v
            const int d0 = (t & 1) * 16;
            const int ocrow = g * CIN + h * HD + d0 + l15;
            const float bias = pwb[ocrow];
            f32x4 acc0 = {bias, bias, bias, bias};
            f32x4 acc1 = {bias, bias, bias, bias};
            bf16x8 bfr[6];
            if (wbf) {
                const u16* wp = wbf + (size_t)ocrow * CIN + l4 * 8;
#pragma unroll
                for (int kt = 0; kt < 6; ++kt) bfr[kt] = *(const bf16x8*)(wp + kt * 32);
            } else {
                const float* wp = pww + (size_t)ocrow * CIN + l4 * 8;
#pragma unroll
                for (int kt = 0; kt < 6; ++kt) {
                    union { u16 u[8]; bf16x8 v; } cv;
#pragma unroll
                    for (int i = 0; i < 8; ++i) cv.u[i] = f2bf(wp[kt * 32 + i]);
                    bfr[kt] = cv.v;
                }
            }
#pragma unroll
            for (int kt = 0; kt < 6; ++kt) {
                acc0 = __builtin_amdgcn_mfma_f32_16x16x32_bf16(afr[0][kt], bfr[kt], acc0, 0, 0, 0);
                acc1 = __builtin_amdgcn_mfma_f32_16x16x32_bf16(afr[1][kt], bfr[kt], acc1, 0, 0, 0);
            }
            // D layout: row = (l>>4)*4 + i, col = l&15
#pragma unroll
            for (int rt = 0; rt < 2; ++rt) {
                const f32x4 a = rt ? acc1 : acc0;
                const int pxr = wr * 32 + rt * 16 + l4 * 4;
#pragma unroll
                for (int i = 0; i < 4; ++i) {
                    const u16 bits = f2bf(a[i]);
                    if (g == 0)      qs[pxr + i][d0 + l15] = bits;
                    else if (g == 1) kk_s[pxr + i][d0 + l15] = bits;
                    else             vt[d0 + l15][pxr + i] = bits;   // store V transposed
                }
            }
        }
        __syncthreads();

        // ---------- inverse L2 norms ----------
        if (tid < 128) {
            const int row = tid & 63;
            const u16* src = (tid < 64) ? qs[row] : kk_s[row];
            float s = 0.f;
#pragma unroll
            for (int d = 0; d < HD; d += 2) {
                const unsigned pr = *(const unsigned*)(src + d);
                const float a = __uint_as_float(pr << 16);
                const float c2 = __uint_as_float(pr & 0xffff0000u);
                s += a * a + c2 * c2;
            }
            const float inv = 1.f / fmaxf(sqrtf(s), 1e-12f);
            if (tid < 64) qin[row] = inv; else kin[row] = inv;
        }
        __syncthreads();

        // ---------- QK^T (K=32 in one MFMA) + softmax ----------
        const int m0 = wave * 16;
        const bf16x8 aq = *(const bf16x8*)&qs[m0 + l15][l4 * 8];
        f32x4 sc[4];
#pragma unroll
        for (int ct = 0; ct < 4; ++ct) {
            f32x4 z = {0.f, 0.f, 0.f, 0.f};
            const bf16x8 bk = *(const bf16x8*)&kk_s[ct * 16 + l15][l4 * 8];
            sc[ct] = __builtin_amdgcn_mfma_f32_16x16x32_bf16(aq, bk, z, 0, 0, 0);
        }
        float qiv[4];
#pragma unroll
        for (int i = 0; i < 4; ++i) qiv[i] = qin[m0 + l4 * 4 + i];
#pragma unroll
        for (int ct = 0; ct < 4; ++ct) {
            const float kiv = kin[ct * 16 + l15];
#pragma unroll
            for (int i = 0; i < 4; ++i) sc[ct][i] *= qiv[i] * kiv;
        }
#pragma unroll
        for (int i = 0; i < 4; ++i) {
            float mx = fmaxf(fmaxf(sc[0][i], sc[1][i]), fmaxf(sc[2][i], sc[3][i]));
#pragma unroll
            for (int off = 1; off < 16; off <<= 1) mx = fmaxf(mx, __shfl_xor(mx, off));
            const float e0 = __expf(sc[0][i] - mx), e1 = __expf(sc[1][i] - mx);
            const float e2 = __expf(sc[2][i] - mx), e3 = __expf(sc[3][i] - mx);
            float s = e0 + e1 + e2 + e3;
#pragma unroll
            for (int off = 1; off < 16; off <<= 1) s += __shfl_xor(s, off);
            const float r = 1.f / s;
            sc[0][i] = e0 * r; sc[1][i] = e1 * r; sc[2][i] = e2 * r; sc[3][i] = e3 * r;
        }
#pragma unroll
        for (int ct = 0; ct < 4; ++ct)
#pragma unroll
            for (int i = 0; i < 4; ++i)
                ps[m0 + l4 * 4 + i][ct * 16 + l15] = f2bf(sc[ct][i]);
        __syncthreads();

        // ---------- PV (64x32, K=64) + store ----------
        const bf16x8 ap0 = *(const bf16x8*)&ps[m0 + l15][l4 * 8];
        const bf16x8 ap1 = *(const bf16x8*)&ps[m0 + l15][32 + l4 * 8];
#pragma unroll
        for (int nt = 0; nt < 2; ++nt) {
            f32x4 oa = {0.f, 0.f, 0.f, 0.f};
            const bf16x8 bv0 = *(const bf16x8*)&vt[nt * 16 + l15][l4 * 8];
            const bf16x8 bv1 = *(const bf16x8*)&vt[nt * 16 + l15][32 + l4 * 8];
            oa = __builtin_amdgcn_mfma_f32_16x16x32_bf16(ap0, bv0, oa, 0, 0, 0);
            oa = __builtin_amdgcn_mfma_f32_16x16x32_bf16(ap1, bv1, oa, 0, 0, 0);
            const int dim = h * HD + nt * 16 + l15;
            const int pxr = m0 + l4 * 4;
            const int py = r0 + (pxr >> 3), pxc = c0 + (pxr & 7);
            float* op = out + (((size_t)(b * CIN + dim)) << 16) + py * IMG + pxc;
            *(f32x4*)op = oa;   // 4 consecutive px
        }
        __syncthreads();
    }
}

__global__ void cvt_w(const float* __restrict__ w, u16* __restrict__ o, int n) {
    const int i = blockIdx.x * 256 + threadIdx.x;
    if (i < n) o[i] = f2bf(w[i]);
}

extern "C" void kernel_launch(void* const* d_in, const int* in_sizes, int n_in,
                              void* d_out, int out_size, void* d_ws, size_t ws_size,
                              hipStream_t stream) {
    const float* x   = (const float*)d_in[0];
    const float* dww = (const float*)d_in[1];
    const float* dwb = (const float*)d_in[2];
    const float* pww = (const float*)d_in[3];
    const float* pwb = (const float*)d_in[4];
    float* out = (float*)d_out;

    const int nw = 3 * CIN * CIN;                 // 110592 weights
    u16* wbf = nullptr;
    if (ws_size >= (size_t)nw * sizeof(u16)) {
        wbf = (u16*)d_ws;
        hipLaunchKernelGGL(cvt_w, dim3(nw / 256), dim3(256), 0, stream, pww, wbf, nw);
    }
    hipLaunchKernelGGL(fused_winattn_mfma, dim3(4 * 32 * 32), dim3(256), 0, stream,
                       x, dww, dwb, pww, pwb, wbf, out);
}